// Round 7
// baseline (499.548 us; speedup 1.0000x reference)
//
#include <hip/hip_runtime.h>

#define D_MODEL 1024
#define N_HEADS 16
#define D_K     64
#define BATCH   4
#define SEQ     2048
#define MROWS   (BATCH * SEQ)          // 8192
// Q pre-scale: (1/sqrt(64)) * log2(e) so attn uses raw exp2
#define QSCALE  0.18033688011112042f

typedef __bf16 bf16x8 __attribute__((ext_vector_type(8)));
typedef float  f32x4  __attribute__((ext_vector_type(4)));
typedef float  f32x16 __attribute__((ext_vector_type(16)));
typedef unsigned short ushort8 __attribute__((ext_vector_type(8)));
typedef unsigned short ushort4v __attribute__((ext_vector_type(4)));

#if __has_builtin(__builtin_amdgcn_exp2f)
#define EXP2F(x) __builtin_amdgcn_exp2f(x)
#else
#define EXP2F(x) exp2f(x)
#endif

__device__ inline unsigned short f2bf(float f) {
    union { float f; unsigned int u; } v; v.f = f;
    unsigned int u = v.u;
    unsigned int r = (u + 0x7fffu + ((u >> 16) & 1u)) >> 16;
    return (unsigned short)r;
}

__device__ inline void load_lds16(const void* g, void* l) {
    __builtin_amdgcn_global_load_lds(
        (const __attribute__((address_space(1))) unsigned int*)g,
        (__attribute__((address_space(3))) unsigned int*)l, 16, 0, 0);
}

// ---------------- prep: weights fp32 [K][N] -> bf16 [N][K] ----------------
__global__ __launch_bounds__(256) void wprep(const float* __restrict__ Wq,
                                             const float* __restrict__ Wk,
                                             const float* __restrict__ Wv,
                                             const float* __restrict__ Wo,
                                             unsigned short* __restrict__ wt) {
    __shared__ __align__(16) unsigned short t[64][65];
    int w  = blockIdx.z;
    const float* W = (w == 0) ? Wq : (w == 1) ? Wk : (w == 2) ? Wv : Wo;
    int k0 = blockIdx.x * 64, n0 = blockIdx.y * 64;
    int tid = threadIdx.x;
    int nl = tid & 63, kq = tid >> 6;
#pragma unroll
    for (int i = 0; i < 16; i++) {
        int kl = kq * 16 + i;
        t[kl][nl] = f2bf(W[(size_t)(k0 + kl) * D_MODEL + n0 + nl]);
    }
    __syncthreads();
    unsigned short* out = wt + (size_t)w * D_MODEL * D_MODEL;
#pragma unroll
    for (int p = 0; p < 2; p++) {
        int nrow = p * 32 + (tid >> 3);
        int c8   = (tid & 7) * 8;
        ushort8 o;
#pragma unroll
        for (int j = 0; j < 8; j++) o[j] = t[c8 + j][nrow];
        *reinterpret_cast<ushort8*>(out + (size_t)(n0 + nrow) * D_MODEL + k0 + c8) = o;
    }
}

// ---------------- prep: x fp32 -> bf16 ----------------
__global__ __launch_bounds__(256) void xprep(const float4* __restrict__ x,
                                             unsigned short* __restrict__ xb) {
    int i = blockIdx.x * 256 + threadIdx.x;
    float4 v = x[i];
    ushort4v o;
    o[0] = f2bf(v.x); o[1] = f2bf(v.y); o[2] = f2bf(v.z); o[3] = f2bf(v.w);
    *reinterpret_cast<ushort4v*>(xb + (size_t)i * 4) = o;
}

// ---------------- prep: mask int32 -> bitmask (bit=1 means masked) --------
__global__ __launch_bounds__(256) void mprep(const int* __restrict__ mask,
                                             unsigned long long* __restrict__ mb) {
    int row = blockIdx.x;
    int tid = threadIdx.x;
    int wv  = tid >> 6;
#pragma unroll
    for (int w = 0; w < 8; w++) {
        int col = w * 256 + tid;
        int mval = mask[(size_t)row * SEQ + col];
        unsigned long long bits = __ballot(mval != 0);
        if ((tid & 63) == 0) mb[(size_t)row * 32 + w * 4 + wv] = bits;
    }
}

// ============ fused QKV GEMM: m97 structure, M=8192 N=3072 K=1024 =========
__global__ __launch_bounds__(256) void qkv_gemm(const unsigned short* __restrict__ xb,
                                                const unsigned short* __restrict__ wt,
                                                const float* __restrict__ bq,
                                                const float* __restrict__ bk,
                                                const float* __restrict__ bvv,
                                                unsigned short* __restrict__ qb,
                                                unsigned short* __restrict__ kb,
                                                unsigned short* __restrict__ vt) {
    __shared__ __align__(16) unsigned short lds_a[128 * 32];
    __shared__ __align__(16) unsigned short lds_b[128 * 32];
    int tid = threadIdx.x;
    int wave = tid >> 6, lane = tid & 63;
    int c = lane & 15, g = lane >> 4;
    int wave_m = (wave & 1) * 64, wave_n = (wave >> 1) * 64;
    int nblk = blockIdx.x * 128, mblk = blockIdx.y * 128;

    int oct0 = wave * 128 + lane, oct1 = oct0 + 64;
    int ra0 = oct0 >> 2, ga0 = ((oct0 & 3) ^ (ra0 & 3)) * 8;
    int ra1 = oct1 >> 2, ga1 = ((oct1 & 3) ^ (ra1 & 3)) * 8;
    const unsigned short* pa0 = xb + (size_t)(mblk + ra0) * D_MODEL + ga0;
    const unsigned short* pa1 = xb + (size_t)(mblk + ra1) * D_MODEL + ga1;
    const unsigned short* pb0 = wt + (size_t)(nblk + ra0) * D_MODEL + ga0;
    const unsigned short* pb1 = wt + (size_t)(nblk + ra1) * D_MODEL + ga1;
    unsigned short* la0 = lds_a + wave * 1024;
    unsigned short* la1 = la0 + 512;
    unsigned short* lb0 = lds_b + wave * 1024;
    unsigned short* lb1 = lb0 + 512;

    int aoff[4], boff[4];
#pragma unroll
    for (int mi = 0; mi < 4; mi++) {
        int row = wave_m + mi * 16 + c;
        aoff[mi] = (row * 4 + (g ^ (row & 3))) * 16;
    }
#pragma unroll
    for (int ni = 0; ni < 4; ni++) {
        int row = wave_n + ni * 16 + c;
        boff[ni] = (row * 4 + (g ^ (row & 3))) * 16;
    }

    f32x4 acc[4][4];
#pragma unroll
    for (int mi = 0; mi < 4; mi++)
#pragma unroll
        for (int ni = 0; ni < 4; ni++) acc[mi][ni] = f32x4{0.f, 0.f, 0.f, 0.f};

    for (int k0 = 0; k0 < D_MODEL; k0 += 32) {
        load_lds16(pa0 + k0, la0);
        load_lds16(pa1 + k0, la1);
        load_lds16(pb0 + k0, lb0);
        load_lds16(pb1 + k0, lb1);
        __syncthreads();
        bf16x8 af[4], bfr[4];
#pragma unroll
        for (int mi = 0; mi < 4; mi++)
            af[mi] = *reinterpret_cast<const bf16x8*>(reinterpret_cast<const char*>(lds_a) + aoff[mi]);
#pragma unroll
        for (int ni = 0; ni < 4; ni++)
            bfr[ni] = *reinterpret_cast<const bf16x8*>(reinterpret_cast<const char*>(lds_b) + boff[ni]);
#pragma unroll
        for (int mi = 0; mi < 4; mi++)
#pragma unroll
            for (int ni = 0; ni < 4; ni++)
                acc[mi][ni] = __builtin_amdgcn_mfma_f32_16x16x32_bf16(af[mi], bfr[ni], acc[mi][ni], 0, 0, 0);
        __syncthreads();
    }

    int nb = nblk + wave_n;
    int wsel = nb >> 10;
    int h = (nb >> 6) & 15;
    int dk0 = nb & 63;
    int mglob = mblk + wave_m;
    int b = mglob >> 11;
    int s0 = mglob & (SEQ - 1);
    size_t bh = (size_t)(b * N_HEADS + h);
    const float* bias = (wsel == 0) ? bq : (wsel == 1) ? bk : bvv;
    int nn = nb & (D_MODEL - 1);
    float bval[4];
#pragma unroll
    for (int ni = 0; ni < 4; ni++) bval[ni] = bias[nn + ni * 16 + c];
    float oscale = (wsel == 0) ? QSCALE : 1.0f;

    if (wsel < 2) {
        unsigned short* outp = wsel ? kb : qb;
#pragma unroll
        for (int mi = 0; mi < 4; mi++)
#pragma unroll
            for (int ni = 0; ni < 4; ni++) {
                int dk = dk0 + ni * 16 + c;
#pragma unroll
                for (int r = 0; r < 4; r++) {
                    int s = s0 + mi * 16 + g * 4 + r;
                    outp[(bh * SEQ + s) * 64 + dk] = f2bf((acc[mi][ni][r] + bval[ni]) * oscale);
                }
            }
    } else {
#pragma unroll
        for (int mi = 0; mi < 4; mi++)
#pragma unroll
            for (int ni = 0; ni < 4; ni++) {
                int dk = dk0 + ni * 16 + c;
                int s = s0 + mi * 16 + g * 4;
                ushort4v o;
#pragma unroll
                for (int r = 0; r < 4; r++) o[r] = f2bf(acc[mi][ni][r] + bval[ni]);
                *reinterpret_cast<ushort4v*>(vt + (bh * 64 + dk) * SEQ + s) = o;
            }
    }
}

// ==== flash attention v7: 64 q/wave, split-K over key halves, 26.6KB LDS ===
// fixed-shift softmax -> partials combine linearly: O=(S1+S2)/(l1+l2)
__global__ __launch_bounds__(128, 3) void attn(const unsigned short* __restrict__ qb,
                                               const unsigned short* __restrict__ kb,
                                               const unsigned short* __restrict__ vt,
                                               const unsigned long long* __restrict__ mb,
                                               unsigned short* __restrict__ pp0,
                                               unsigned short* __restrict__ pp1,
                                               float* __restrict__ lsw) {
    __shared__ __align__(16) unsigned char smem[26624];
    unsigned short* lk = (unsigned short*)smem;            // [64 key][64 dk], octet^row&7
    unsigned short* lv = (unsigned short*)(smem + 8192);   // [64 dk][64 key], octet^row&7
    unsigned int*  lpA = (unsigned int*)(smem + 16384);    // P: wave*1280 + t*640 + q*20

    int tid = threadIdx.x;
    int wave = tid >> 6, lane = tid & 63;
    int q31 = lane & 31, hi = lane >> 5;
    int ks = blockIdx.x & 1;                     // key half
    int qblk = (blockIdx.x >> 1) & 15;
    int bh = blockIdx.x >> 5;
    int q0 = qblk * 128 + wave * 64;
    int b = bh >> 4, h = bh & 15;
    const unsigned short* qbase = qb + (size_t)bh * SEQ * 64;
    const unsigned short* kbase = kb + (size_t)bh * SEQ * 64;
    const unsigned short* vbase = vt + (size_t)bh * 64 * SEQ;
    const unsigned long long* mp0 = mb + ((size_t)b * SEQ + q0 + q31) * 32 + ks * 16;
    const unsigned long long* mp1 = mp0 + 1024;   // +32 rows * 32 words

    // Q B-frags for both tiles: chunk c covers dk = 16c + 8hi + (0..7)
    bf16x8 qf[2][4];
#pragma unroll
    for (int t = 0; t < 2; t++) {
        const unsigned short* qr = qbase + (size_t)(q0 + 32 * t + q31) * 64 + hi * 8;
#pragma unroll
        for (int c = 0; c < 4; c++)
            qf[t][c] = *reinterpret_cast<const bf16x8*>(qr + c * 16);
    }

    // staging: 8 rows x 128B per glds; octet xor (row&7)
    int srow = lane >> 3;
    int soct = (lane & 7) ^ srow;
    const unsigned short* ksrc[4];
    const unsigned short* vsrc[4];
    unsigned short* klb[4];
    unsigned short* vlb[4];
#pragma unroll
    for (int i = 0; i < 4; i++) {
        int rbase = 16 * i + 8 * wave;
        ksrc[i] = kbase + (size_t)(rbase + srow) * 64 + soct * 8 + (size_t)ks * 1024 * 64;
        vsrc[i] = vbase + (size_t)(rbase + srow) * SEQ + soct * 8 + ks * 1024;
        klb[i] = lk + rbase * 64;
        vlb[i] = lv + rbase * 64;
    }

    // K/V fragment byte offsets: subtile s (rows 32s..), chunk c
    int kofs[2][4];
#pragma unroll
    for (int s = 0; s < 2; s++)
#pragma unroll
        for (int c = 0; c < 4; c++)
            kofs[s][c] = (32 * s + q31) * 128 + (((hi + 2 * c) ^ (q31 & 7)) * 16);

    unsigned int* lp = lpA + wave * 1280 + q31 * 20;   // + t*640

    float lsum[2] = {0.f, 0.f};
    f32x16 po[2][2];
#pragma unroll
    for (int i = 0; i < 16; i++) {
        po[0][0][i] = 0.f; po[0][1][i] = 0.f;
        po[1][0][i] = 0.f; po[1][1][i] = 0.f;
    }

    for (int it = 0; it < 16; it++) {
#pragma unroll
        for (int i = 0; i < 4; i++) {
            load_lds16(ksrc[i] + it * 4096, klb[i]);
            load_lds16(vsrc[i] + it * 64, vlb[i]);
        }
        unsigned long long w64[2];
        w64[0] = mp0[it];
        w64[1] = mp1[it];
        __syncthreads();

        const char* lkb = (const char*)lk;
        const char* lvb = (const char*)lv;

#pragma unroll
        for (int s = 0; s < 2; s++) {
            // QK^T (S^T): A=K rows(keys 32s..32s+31), B=Q[t] -> col=query
            f32x16 sq[2];
#pragma unroll
            for (int i = 0; i < 16; i++) { sq[0][i] = 0.f; sq[1][i] = 0.f; }
#pragma unroll
            for (int c = 0; c < 4; c++) {
                bf16x8 kf = *reinterpret_cast<const bf16x8*>(lkb + kofs[s][c]);
                sq[0] = __builtin_amdgcn_mfma_f32_32x32x16_bf16(kf, qf[0][c], sq[0], 0, 0, 0);
                sq[1] = __builtin_amdgcn_mfma_f32_32x32x16_bf16(kf, qf[1][c], sq[1], 0, 0, 0);
            }
            // softmax numerators; key(within subtile) = 8j + 4hi + e
#pragma unroll
            for (int t = 0; t < 2; t++) {
                unsigned int wt_ = ~(unsigned int)(w64[t] >> (32 * s));   // bit=1 -> keep
                unsigned int* pw = lp + t * 640;
#pragma unroll
                for (int j = 0; j < 4; j++) {
                    unsigned int nj = wt_ >> (8 * j + 4 * hi);
                    unsigned int t0, t1, t2, t3;
                    {
                        float p = EXP2F(sq[t][4 * j + 0]);
                        unsigned int m = (unsigned int)((int)(nj << 31) >> 31);
                        t0 = __float_as_uint(p) & m; lsum[t] += __uint_as_float(t0);
                    }
                    {
                        float p = EXP2F(sq[t][4 * j + 1]);
                        unsigned int m = (unsigned int)((int)(nj << 30) >> 31);
                        t1 = __float_as_uint(p) & m; lsum[t] += __uint_as_float(t1);
                    }
                    {
                        float p = EXP2F(sq[t][4 * j + 2]);
                        unsigned int m = (unsigned int)((int)(nj << 29) >> 31);
                        t2 = __float_as_uint(p) & m; lsum[t] += __uint_as_float(t2);
                    }
                    {
                        float p = EXP2F(sq[t][4 * j + 3]);
                        unsigned int m = (unsigned int)((int)(nj << 28) >> 31);
                        t3 = __float_as_uint(p) & m; lsum[t] += __uint_as_float(t3);
                    }
                    uint2 u;
                    u.x = (t0 >> 16) | (t1 & 0xFFFF0000u);
                    u.y = (t2 >> 16) | (t3 & 0xFFFF0000u);
                    *reinterpret_cast<uint2*>(pw + 4 * j + 2 * hi) = u;
                }
            }
            // PV (O^T): chunks c = 2s, 2s+1; A=V^T rows(dk), B=P^T -> col=query
#pragma unroll
            for (int cp = 0; cp < 2; cp++) {
                int c = 2 * s + cp;
                union { bf16x8 v; uint4 u; } pb0, pb1;
                pb0.u = *reinterpret_cast<const uint4*>(lp + 0 * 640 + 8 * cp + 4 * hi);
                pb1.u = *reinterpret_cast<const uint4*>(lp + 1 * 640 + 8 * cp + 4 * hi);
#pragma unroll
                for (int so = 0; so < 2; so++) {
                    bf16x8 vf = *reinterpret_cast<const bf16x8*>(lvb + kofs[so][c]);
                    po[0][so] = __builtin_amdgcn_mfma_f32_32x32x16_bf16(vf, pb0.v, po[0][so], 0, 0, 0);
                    po[1][so] = __builtin_amdgcn_mfma_f32_32x32x16_bf16(vf, pb1.v, po[1][so], 0, 0, 0);
                }
            }
        }
        __syncthreads();
    }

    // finish partial row sums (partner lane^32 holds complementary key half)
    float ls[2];
#pragma unroll
    for (int t = 0; t < 2; t++)
        ls[t] = lsum[t] + __shfl_xor(lsum[t], 32);
    if (hi == 0) {
        int base = ks * (64 * SEQ) + bh * SEQ + q0;
        lsw[base + q31]      = ls[0];
        lsw[base + 32 + q31] = ls[1];
    }

    // epilogue: UNNORMALIZED partial O^T (dk = 32so+8j+4hi+e), bounce via LDS
    unsigned int* ob = (unsigned int*)(smem + wave * 8192);
    int csw = 4 * (q31 & 7);
#pragma unroll
    for (int t = 0; t < 2; t++) {
        unsigned int* obr = ob + (32 * t + q31) * 32;
#pragma unroll
        for (int so = 0; so < 2; so++)
#pragma unroll
            for (int j = 0; j < 4; j++) {
                unsigned int w0 = (unsigned int)f2bf(po[t][so][4 * j + 0])
                                | ((unsigned int)f2bf(po[t][so][4 * j + 1]) << 16);
                unsigned int w1 = (unsigned int)f2bf(po[t][so][4 * j + 2])
                                | ((unsigned int)f2bf(po[t][so][4 * j + 3]) << 16);
                int d = (16 * so + 4 * j + 2 * hi) ^ csw;
                uint2 u; u.x = w0; u.y = w1;
                *reinterpret_cast<uint2*>(obr + d) = u;
            }
    }
    __builtin_amdgcn_s_waitcnt(0);   // drain own ds_writes (wave-private region)
    unsigned short* pp = ks ? pp1 : pp0;
    size_t crow = (size_t)b * SEQ + q0;
    int o = lane & 7, rl = lane >> 3;
#pragma unroll
    for (int i = 0; i < 8; i++) {
        int r = 8 * i + rl;
        uint4 v = *reinterpret_cast<const uint4*>(ob + r * 32 + 4 * (o ^ (r & 7)));
        *reinterpret_cast<uint4*>(pp + (crow + r) * D_MODEL + h * 64 + o * 8) = v;
    }
}

// ---------------- combine split-K partials: ctx = (p0+p1)/(l0+l1) ---------
__global__ __launch_bounds__(256) void combine(const unsigned short* __restrict__ p0,
                                               const unsigned short* __restrict__ p1,
                                               const float* __restrict__ lsw,
                                               unsigned short* __restrict__ outp) {
    int i = blockIdx.x * 256 + threadIdx.x;      // 8-elem groups over MROWS*D_MODEL
    int row = i >> 7;                            // global q-row [0,8192)
    int col8 = i & 127;
    int b = row >> 11, s = row & 2047, h = col8 >> 3;
    int bhq = (((b << 4) + h) << 11) + s;
    float inv = 1.f / (lsw[bhq] + lsw[64 * SEQ + bhq]);
    ushort8 a = *reinterpret_cast<const ushort8*>(p0 + (size_t)i * 8);
    ushort8 c = *reinterpret_cast<const ushort8*>(p1 + (size_t)i * 8);
    ushort8 o;
#pragma unroll
    for (int j = 0; j < 8; j++) {
        float fa = __uint_as_float((unsigned int)a[j] << 16);
        float fc = __uint_as_float((unsigned int)c[j] << 16);
        o[j] = f2bf((fa + fc) * inv);
    }
    *reinterpret_cast<ushort8*>(outp + (size_t)i * 8) = o;
}

// ============ output projection: m97 structure, M=8192 N=1024 K=1024 ======
__global__ __launch_bounds__(256) void oproj(const unsigned short* __restrict__ ctx,
                                             const unsigned short* __restrict__ wt,
                                             const float* __restrict__ bo,
                                             float* __restrict__ out) {
    __shared__ __align__(16) unsigned short lds_a[128 * 32];
    __shared__ __align__(16) unsigned short lds_b[128 * 32];
    int tid = threadIdx.x;
    int wave = tid >> 6, lane = tid & 63;
    int c = lane & 15, g = lane >> 4;
    int wave_m = (wave & 1) * 64, wave_n = (wave >> 1) * 64;
    int nblk = blockIdx.x * 128, mblk = blockIdx.y * 128;
    const unsigned short* wo = wt + (size_t)3 * D_MODEL * D_MODEL;

    int oct0 = wave * 128 + lane, oct1 = oct0 + 64;
    int ra0 = oct0 >> 2, ga0 = ((oct0 & 3) ^ (ra0 & 3)) * 8;
    int ra1 = oct1 >> 2, ga1 = ((oct1 & 3) ^ (ra1 & 3)) * 8;
    const unsigned short* pa0 = ctx + (size_t)(mblk + ra0) * D_MODEL + ga0;
    const unsigned short* pa1 = ctx + (size_t)(mblk + ra1) * D_MODEL + ga1;
    const unsigned short* pb0 = wo + (size_t)(nblk + ra0) * D_MODEL + ga0;
    const unsigned short* pb1 = wo + (size_t)(nblk + ra1) * D_MODEL + ga1;
    unsigned short* la0 = lds_a + wave * 1024;
    unsigned short* la1 = la0 + 512;
    unsigned short* lb0 = lds_b + wave * 1024;
    unsigned short* lb1 = lb0 + 512;

    int aoff[4], boff[4];
#pragma unroll
    for (int mi = 0; mi < 4; mi++) {
        int row = wave_m + mi * 16 + c;
        aoff[mi] = (row * 4 + (g ^ (row & 3))) * 16;
    }
#pragma unroll
    for (int ni = 0; ni < 4; ni++) {
        int row = wave_n + ni * 16 + c;
        boff[ni] = (row * 4 + (g ^ (row & 3))) * 16;
    }

    f32x4 acc[4][4];
#pragma unroll
    for (int mi = 0; mi < 4; mi++)
#pragma unroll
        for (int ni = 0; ni < 4; ni++) acc[mi][ni] = f32x4{0.f, 0.f, 0.f, 0.f};

    for (int k0 = 0; k0 < D_MODEL; k0 += 32) {
        load_lds16(pa0 + k0, la0);
        load_lds16(pa1 + k0, la1);
        load_lds16(pb0 + k0, lb0);
        load_lds16(pb1 + k0, lb1);
        __syncthreads();
        bf16x8 af[4], bfr[4];
#pragma unroll
        for (int mi = 0; mi < 4; mi++)
            af[mi] = *reinterpret_cast<const bf16x8*>(reinterpret_cast<const char*>(lds_a) + aoff[mi]);
#pragma unroll
        for (int ni = 0; ni < 4; ni++)
            bfr[ni] = *reinterpret_cast<const bf16x8*>(reinterpret_cast<const char*>(lds_b) + boff[ni]);
#pragma unroll
        for (int mi = 0; mi < 4; mi++)
#pragma unroll
            for (int ni = 0; ni < 4; ni++)
                acc[mi][ni] = __builtin_amdgcn_mfma_f32_16x16x32_bf16(af[mi], bfr[ni], acc[mi][ni], 0, 0, 0);
        __syncthreads();
    }

    float bval[4];
#pragma unroll
    for (int ni = 0; ni < 4; ni++) bval[ni] = bo[nblk + wave_n + ni * 16 + c];
#pragma unroll
    for (int mi = 0; mi < 4; mi++)
#pragma unroll
        for (int ni = 0; ni < 4; ni++) {
            int n = nblk + wave_n + ni * 16 + c;
#pragma unroll
            for (int r = 0; r < 4; r++) {
                int m = mblk + wave_m + mi * 16 + g * 4 + r;
                out[(size_t)m * D_MODEL + n] = acc[mi][ni][r] + bval[ni];
            }
        }
}

extern "C" void kernel_launch(void* const* d_in, const int* in_sizes, int n_in,
                              void* d_out, int out_size, void* d_ws, size_t ws_size,
                              hipStream_t stream) {
    const float* x    = (const float*)d_in[0];
    const int*   mask = (const int*)d_in[1];
    const float* Wq = (const float*)d_in[2];
    const float* bq = (const float*)d_in[3];
    const float* Wk = (const float*)d_in[4];
    const float* bk = (const float*)d_in[5];
    const float* Wv = (const float*)d_in[6];
    const float* bv = (const float*)d_in[7];
    const float* Wo = (const float*)d_in[8];
    const float* bo = (const float*)d_in[9];
    float* out = (float*)d_out;

    char* ws = (char*)d_ws;
    const size_t MB = 1024 * 1024;
    unsigned short* wt  = (unsigned short*)(ws + 0 * MB);    // 8 MB
    unsigned short* xb  = (unsigned short*)(ws + 8 * MB);    // 16 MB (reused: ks=1 partial)
    unsigned short* qb  = (unsigned short*)(ws + 24 * MB);   // 16 MB
    unsigned short* kb  = (unsigned short*)(ws + 40 * MB);   // 16 MB
    unsigned short* vt  = (unsigned short*)(ws + 56 * MB);   // 16 MB
    unsigned short* ctx = (unsigned short*)(ws + 72 * MB);   // 16 MB (ks=0 partial, then final)
    unsigned long long* mb = (unsigned long long*)(ws + 88 * MB); // 2 MB
    float* lsw = (float*)(ws + 90 * MB);                     // 2 x 64 x 2048 fp32 = 1 MB

    wprep<<<dim3(16, 16, 4), 256, 0, stream>>>(Wq, Wk, Wv, Wo, wt);
    xprep<<<dim3(MROWS * D_MODEL / 4 / 256), 256, 0, stream>>>((const float4*)x, xb);
    mprep<<<dim3(MROWS), 256, 0, stream>>>(mask, mb);
    qkv_gemm<<<dim3(24, 64), 256, 0, stream>>>(xb, wt, bq, bk, bv, qb, kb, vt);
    attn<<<dim3(2048), 128, 0, stream>>>(qb, kb, vt, mb, ctx, xb, lsw);
    combine<<<dim3(MROWS * D_MODEL / 8 / 256), 256, 0, stream>>>(ctx, xb, lsw, ctx);
    oproj<<<dim3(8, 64), 256, 0, stream>>>(ctx, wt, bo, out);
}